// Round 10
// baseline (331.355 us; speedup 1.0000x reference)
//
#include <hip/hip_runtime.h>
#include <stdint.h>
#include <stddef.h>

// Problem constants (B=4, L=1024, D=768, H=6, DH=128)
#define BB 4
#define LL 1024
#define DD 768
#define HH 6
#define DHH 128
#define EPS 1e-5f

// Inputs fp32, outputs fp32.
// Output layout (fp32 elements, concatenated in return order):
//   co : (B,H,L,L) = 25165824
//   w  : (B,L,1)   = 4096
//   Vh : (B,H,L,DH)= 3145728
#define CO_ELEMS 25165824
#define W_ELEMS  4096

// ws layout (fp32 elements), ~3.9 MB. Deterministic writes, no atomics.
// Gram partials (25 MB) live in the co OUTPUT region as scratch — k_fused
// fully overwrites co afterwards.
#define OFF_Q2  0           // 24576
#define OFF_K2  24576       // 24576
#define OFF_WC  49152       // 24576  final col sums
#define OFF_SM  73728       // 48*8*260 = 99840 (sv[128],tv[128],s2,s22)
#define OFF_AC  173568      // 16     a1[0..7], c1[8..15]
#define OFF_GDP 173584      // 192    gram-dot partials (24*8)
#define OFF_SS  173776      // 192    BN2 (sum,sumsq) block partials
#define OFF_WP  174080      // 32*24*1024 = 786432 col-sum strip partials
// total 960512 floats = 3.84 MB

typedef __attribute__((ext_vector_type(8))) short short8;
typedef __attribute__((ext_vector_type(4))) float f32x4;

// load 8 contiguous fp32, truncate to bf16 fragment
__device__ __forceinline__ short8 ld_bf8(const float* __restrict__ p) {
    const float4 a = *(const float4*)(p);
    const float4 b = *(const float4*)(p + 4);
    short8 r;
    r[0] = (short)(__float_as_uint(a.x) >> 16);
    r[1] = (short)(__float_as_uint(a.y) >> 16);
    r[2] = (short)(__float_as_uint(a.z) >> 16);
    r[3] = (short)(__float_as_uint(a.w) >> 16);
    r[4] = (short)(__float_as_uint(b.x) >> 16);
    r[5] = (short)(__float_as_uint(b.y) >> 16);
    r[6] = (short)(__float_as_uint(b.z) >> 16);
    r[7] = (short)(__float_as_uint(b.w) >> 16);
    return r;
}

// ------------------------------------------------- q2 / k2 (row sq-norms)
__global__ void k_rownorm(const float* __restrict__ Q,
                          const float* __restrict__ K,
                          float* __restrict__ ws) {
    int gid = blockIdx.x * 256 + threadIdx.x;       // 196608
    int sub = gid & 3;
    int rg  = gid >> 2;
    int which = (rg >= 24576);
    int rid = which ? rg - 24576 : rg;              // bh*1024 + i
    int bh = rid >> 10, i = rid & 1023;
    int b = bh / HH, h = bh - b * HH;
    const float* src = (which ? K : Q) + (size_t)(b * LL + i) * DD + h * DHH;
    float s = 0.f;
#pragma unroll
    for (int kk = 0; kk < 8; kk++) {
        float4 v = *(const float4*)(src + (sub + 4 * kk) * 4);
        s += v.x * v.x + v.y * v.y + v.z * v.z + v.w * v.w;
    }
    s += __shfl_xor(s, 1);
    s += __shfl_xor(s, 2);
    if (sub == 0) ws[(which ? OFF_K2 : OFF_Q2) + rid] = s;
}

// ------------------------------------------------- Vh output (exact copy)
__global__ void k_vh(const float* __restrict__ V, float* __restrict__ out) {
    int cid = blockIdx.x * 256 + threadIdx.x;       // 786432 float4 chunks
    if (cid >= 786432) return;
    int d4 = cid & 31;
    int rest = cid >> 5;
    int l = rest & 1023;
    int bh = rest >> 10;
    int b = bh / HH, h = bh - b * HH;
    f32x4 v = *(const f32x4*)(V + (size_t)(b * LL + l) * DD + h * DHH + d4 * 4);
    __builtin_nontemporal_store(v, (f32x4*)(out + (size_t)cid * 4));
}

// ---- Gram partial (8-way K-split) + sv/tv/s2/s22 sums, same LDS tile.
// grid (24 bh, 2 which, 8 ks); block 256 = 4 waves (64x64 Gram quadrant each)
__global__ __launch_bounds__(256) void k_gramsum(
        const float* __restrict__ Q, const float* __restrict__ Km,
        const float* __restrict__ ws, float* __restrict__ gramS,
        float* __restrict__ smP) {
    const int bh = blockIdx.x, which = blockIdx.y, ks = blockIdx.z;
    const int b = bh / HH, h = bh - b * HH;
    const float* X  = (which ? Km : Q) + (size_t)b * LL * DD + h * DHH;
    const float* x2 = ws + (which ? OFF_K2 : OFF_Q2) + bh * 1024;
    const int rbase = ks * 128;
    const int tid = threadIdx.x, lane = tid & 63, wave = tid >> 6;
    const int lm = lane & 15, quad = lane >> 4;
    const int m0 = (wave >> 1) * 64, n0 = (wave & 1) * 64;
    __shared__ float xs[32 * 132];
    __shared__ float xs2[32];
    f32x4 acc[4][4];
#pragma unroll
    for (int mi = 0; mi < 4; mi++)
#pragma unroll
        for (int ni = 0; ni < 4; ni++) acc[mi][ni] = (f32x4)(0.0f);
    float sv = 0.f, tv = 0.f, s2p = 0.f, s22p = 0.f;

    for (int kc = 0; kc < 4; kc++) {
        __syncthreads();
#pragma unroll
        for (int s = 0; s < 4; s++) {
            int fidx = s * 256 + tid;
            int row = fidx >> 5, c4 = fidx & 31;
            float4 v = *(const float4*)(X + (size_t)(rbase + kc * 32 + row) * DD + c4 * 4);
            *(float4*)&xs[row * 132 + c4 * 4] = v;
        }
        if (tid < 32) xs2[tid] = x2[rbase + kc * 32 + tid];
        __syncthreads();
        short8 am[4], bn[4];
#pragma unroll
        for (int mi = 0; mi < 4; mi++) {
            short8 f;
#pragma unroll
            for (int j = 0; j < 8; j++) {
                float v = xs[(quad * 8 + j) * 132 + m0 + mi * 16 + lm];
                f[j] = (short)(__float_as_uint(v) >> 16);
            }
            am[mi] = f;
        }
#pragma unroll
        for (int ni = 0; ni < 4; ni++) {
            short8 f;
#pragma unroll
            for (int j = 0; j < 8; j++) {
                float v = xs[(quad * 8 + j) * 132 + n0 + ni * 16 + lm];
                f[j] = (short)(__float_as_uint(v) >> 16);
            }
            bn[ni] = f;
        }
#pragma unroll
        for (int mi = 0; mi < 4; mi++)
#pragma unroll
            for (int ni = 0; ni < 4; ni++)
                acc[mi][ni] = __builtin_amdgcn_mfma_f32_16x16x32_bf16(am[mi], bn[ni], acc[mi][ni], 0, 0, 0);
        if (tid < 128) {
#pragma unroll 4
            for (int row = 0; row < 32; row++) {
                float v = xs[row * 132 + tid];
                sv += v; tv += xs2[row] * v;
            }
        }
        if (tid < 32) { float w2 = xs2[tid]; s2p += w2; s22p += w2 * w2; }
    }

    float* G = gramS + (size_t)((which * 24 + bh) * 8 + ks) * 16384;
#pragma unroll
    for (int mi = 0; mi < 4; mi++)
#pragma unroll
        for (int ni = 0; ni < 4; ni++)
#pragma unroll
            for (int r = 0; r < 4; r++)
                G[(m0 + mi * 16 + quad * 4 + r) * 128 + (n0 + ni * 16 + lm)] = acc[mi][ni][r];

    float* sm = smP + (size_t)((which * 24 + bh) * 8 + ks) * 260;
    if (tid < 128) { sm[tid] = sv; sm[128 + tid] = tv; }
    if (tid < 32) {
#pragma unroll
        for (int off = 1; off < 32; off <<= 1) {
            s2p += __shfl_xor(s2p, off);
            s22p += __shfl_xor(s22p, off);
        }
        if (tid == 0) { sm[256] = s2p; sm[257] = s22p; }
    }
}

// ---- Frobenius dot <Gq,Gk> partials: grid (24, 8)
__global__ void k_gdot(const float* __restrict__ gramS, float* __restrict__ gdP) {
    const int bh = blockIdx.x, part = blockIdx.y, t = threadIdx.x;
    const float* gq = gramS + (size_t)(bh * 8) * 16384;
    const float* gk = gramS + (size_t)((24 + bh) * 8) * 16384;
    float s = 0.f;
#pragma unroll
    for (int it = 0; it < 8; it++) {
        int e = part * 2048 + it * 256 + t;
        float a = 0.f, b = 0.f;
#pragma unroll
        for (int ks = 0; ks < 8; ks++) {
            a += gq[(size_t)ks * 16384 + e];
            b += gk[(size_t)ks * 16384 + e];
        }
        s += a * b;
    }
#pragma unroll
    for (int off = 1; off < 64; off <<= 1) s += __shfl_xor(s, off);
    __shared__ float sc[4];
    if ((t & 63) == 0) sc[t >> 6] = s;
    __syncthreads();
    if (t == 0) gdP[bh * 8 + part] = sc[0] + sc[1] + sc[2] + sc[3];
}

// ---- closed-form BN1 stats -> a1, c1 per head (parallel: 8 threads per bh)
__global__ void k_stats2(const float* __restrict__ smP, const float* __restrict__ gdP,
                         const float* __restrict__ g1, const float* __restrict__ b1,
                         float* __restrict__ ac) {
    const int t = threadIdx.x;           // 256
    const int bh = t >> 3, sl = t & 7;
    double dqk = 0, dtqk = 0, dtkq = 0;
    if (bh < 24) {
        for (int dd = sl * 16; dd < sl * 16 + 16; dd++) {
            float svq = 0.f, svk = 0.f, tvq = 0.f, tvk = 0.f;
#pragma unroll
            for (int ks = 0; ks < 8; ks++) {
                const float* q = smP + (size_t)(bh * 8 + ks) * 260;
                const float* k = smP + (size_t)((24 + bh) * 8 + ks) * 260;
                svq += q[dd]; tvq += q[128 + dd];
                svk += k[dd]; tvk += k[128 + dd];
            }
            dqk  += (double)svq * svk;
            dtqk += (double)tvq * svk;
            dtkq += (double)tvk * svq;
        }
    }
#pragma unroll
    for (int off = 1; off < 8; off <<= 1) {
        dqk  += __shfl_xor(dqk, off);
        dtqk += __shfl_xor(dtqk, off);
        dtkq += __shfl_xor(dtkq, off);
    }
    __shared__ double sA[24], sB[24];
    if (bh < 24 && sl == 0) {
        double s2q = 0, s22q = 0, s2k = 0, s22k = 0, gd = 0;
#pragma unroll
        for (int ks = 0; ks < 8; ks++) {
            const float* q = smP + (size_t)(bh * 8 + ks) * 260;
            const float* k = smP + (size_t)((24 + bh) * 8 + ks) * 260;
            s2q += q[256]; s22q += q[257];
            s2k += k[256]; s22k += k[257];
        }
#pragma unroll
        for (int p = 0; p < 8; p++) gd += gdP[bh * 8 + p];
        sA[bh] = -1024.0 * (s2q + s2k) + 2.0 * dqk;
        sB[bh] = 1024.0 * (s22q + s22k) + 4.0 * gd
               + 2.0 * s2q * s2k - 4.0 * dtqk - 4.0 * dtkq;
    }
    __syncthreads();
    if (t < HH) {
        double hs = 0, hq = 0;
        for (int b = 0; b < 4; b++) { hs += sA[b * HH + t]; hq += sB[b * HH + t]; }
        const double N = 4194304.0;
        double m = hs / N;
        double var = hq / N - m * m;
        if (var < 0) var = 0;
        float r = rsqrtf((float)var + EPS);
        float a = r * g1[t];
        ac[t] = a;
        ac[8 + t] = b1[t] - (float)m * a;
    }
}

// ---- fused: GEMM full-row strip -> BN -> mask -> exp -> row softmax ->
// write p ONCE (scatter dword, proven no amplification); col strip partials.
// Block: 4 waves, 32 rows x 1024 cols; wave owns 32x256 (acc[2][16]).
__global__ __launch_bounds__(256, 2) void k_fused(
        const float* __restrict__ Q, const float* __restrict__ Km,
        const float* __restrict__ q2, const float* __restrict__ k2,
        const float* __restrict__ ac, const unsigned char* __restrict__ bx,
        float* __restrict__ co, float* __restrict__ wcolP) {
    const int strip = blockIdx.x;         // 32 strips of 32 rows
    const int bh = blockIdx.y;            // 24
    const int b = bh / HH, h = bh - b * HH;
    const int tid = threadIdx.x, lane = tid & 63, wave = tid >> 6;
    const int lm = lane & 15, quad = lane >> 4;
    const int ibase = strip * 32;
    const int colbase = wave * 256;
    const float* Qb = Q + (size_t)b * LL * DD + h * DHH;
    const float* Kb = Km + (size_t)b * LL * DD + h * DHH;

    f32x4 acc[2][16];
#pragma unroll
    for (int ti = 0; ti < 2; ti++)
#pragma unroll
        for (int tj = 0; tj < 16; tj++) acc[ti][tj] = (f32x4)(0.0f);

#pragma unroll
    for (int kk = 0; kk < 4; kk++) {
        const int d0 = kk * 32 + quad * 8;
        short8 af0 = ld_bf8(Qb + (size_t)(ibase + lm) * DD + d0);
        short8 af1 = ld_bf8(Qb + (size_t)(ibase + 16 + lm) * DD + d0);
#pragma unroll
        for (int tj = 0; tj < 16; tj++) {
            short8 bf = ld_bf8(Kb + (size_t)(colbase + tj * 16 + lm) * DD + d0);
            acc[0][tj] = __builtin_amdgcn_mfma_f32_16x16x32_bf16(af0, bf, acc[0][tj], 0, 0, 0);
            acc[1][tj] = __builtin_amdgcn_mfma_f32_16x16x32_bf16(af1, bf, acc[1][tj], 0, 0, 0);
        }
    }

    const float a = ac[h], c = ac[8 + h];
    const unsigned char* bxb = bx + b * LL;
    float q2v[8]; bool vi[8];
#pragma unroll
    for (int ti = 0; ti < 2; ti++)
#pragma unroll
        for (int r = 0; r < 4; r++) {
            int i = ibase + ti * 16 + quad * 4 + r;
            q2v[ti * 4 + r] = q2[bh * 1024 + i];
            vi[ti * 4 + r] = (bxb[i] == 0);
        }
    float k2v[16]; bool vj[16];
#pragma unroll
    for (int tj = 0; tj < 16; tj++) {
        int j = colbase + tj * 16 + lm;
        k2v[tj] = k2[bh * 1024 + j];
        vj[tj] = (bxb[j] == 0);
    }

    float rp[8] = {0.f, 0.f, 0.f, 0.f, 0.f, 0.f, 0.f, 0.f};
#pragma unroll
    for (int ti = 0; ti < 2; ti++)
#pragma unroll
        for (int tj = 0; tj < 16; tj++)
#pragma unroll
            for (int r = 0; r < 4; r++) {
                float S = 2.0f * acc[ti][tj][r] - q2v[ti * 4 + r] - k2v[tj];
                float z = (vi[ti * 4 + r] && vj[tj]) ? fminf(a * S + c, 60.0f) : 0.0f;
                float e = __expf(z);
                acc[ti][tj][r] = e;
                rp[ti * 4 + r] += e;
            }

#pragma unroll
    for (int u = 0; u < 8; u++) {
        rp[u] += __shfl_xor(rp[u], 1);
        rp[u] += __shfl_xor(rp[u], 2);
        rp[u] += __shfl_xor(rp[u], 4);
        rp[u] += __shfl_xor(rp[u], 8);
    }
    __shared__ float rs[32][5];
    __shared__ float invs[32];
    __shared__ float colsum[1024];
    if (lm == 0) {
#pragma unroll
        for (int ti = 0; ti < 2; ti++)
#pragma unroll
            for (int r = 0; r < 4; r++)
                rs[ti * 16 + quad * 4 + r][wave] = rp[ti * 4 + r];
    }
    __syncthreads();
    if (tid < 32) invs[tid] = 1.0f / (rs[tid][0] + rs[tid][1] + rs[tid][2] + rs[tid][3]);
    __syncthreads();
    float iv[8];
#pragma unroll
    for (int ti = 0; ti < 2; ti++)
#pragma unroll
        for (int r = 0; r < 4; r++) iv[ti * 4 + r] = invs[ti * 16 + quad * 4 + r];

    float cs[16];
#pragma unroll
    for (int tj = 0; tj < 16; tj++) cs[tj] = 0.f;
#pragma unroll
    for (int ti = 0; ti < 2; ti++)
#pragma unroll
        for (int tj = 0; tj < 16; tj++)
#pragma unroll
            for (int r = 0; r < 4; r++) {
                float p = acc[ti][tj][r] * iv[ti * 4 + r];
                acc[ti][tj][r] = p;
                cs[tj] += p;
            }

    float* cob = co + ((size_t)bh << 20);
#pragma unroll
    for (int ti = 0; ti < 2; ti++)
#pragma unroll
        for (int tj = 0; tj < 16; tj++)
#pragma unroll
            for (int r = 0; r < 4; r++) {
                int i = ibase + ti * 16 + quad * 4 + r;
                int j = colbase + tj * 16 + lm;
                cob[((size_t)i << 10) + j] = acc[ti][tj][r];
            }

#pragma unroll
    for (int tj = 0; tj < 16; tj++) {
        cs[tj] += __shfl_xor(cs[tj], 16);
        cs[tj] += __shfl_xor(cs[tj], 32);
    }
    if (quad == 0) {
#pragma unroll
        for (int tj = 0; tj < 16; tj++) colsum[colbase + tj * 16 + lm] = cs[tj];
    }
    __syncthreads();
    float4 wv = *(const float4*)&colsum[tid * 4];
    *(float4*)&wcolP[((size_t)strip * 24 + bh) * 1024 + tid * 4] = wv;
}

// ---- reduce col-sum strip partials -> wcol; fused BN2 block partials
__global__ void k_wcol_reduce(const float* __restrict__ wcolP,
                              float* __restrict__ wcol, float* __restrict__ ws2) {
    const int t = threadIdx.x;
    int g = blockIdx.x * 256 + t;                    // 24576
    float s = 0.f;
#pragma unroll 8
    for (int strip = 0; strip < 32; strip++)
        s += wcolP[(size_t)strip * 24576 + g];
    wcol[g] = s;
    float a = s, b = s * s;
#pragma unroll
    for (int off = 1; off < 64; off <<= 1) { a += __shfl_xor(a, off); b += __shfl_xor(b, off); }
    __shared__ float sc[4][2];
    if ((t & 63) == 0) { sc[t >> 6][0] = a; sc[t >> 6][1] = b; }
    __syncthreads();
    if (t == 0) {
        ws2[blockIdx.x * 2]     = sc[0][0] + sc[1][0] + sc[2][0] + sc[3][0];
        ws2[blockIdx.x * 2 + 1] = sc[0][1] + sc[1][1] + sc[2][1] + sc[3][1];
    }
}

// ------- tail: BN2 (from block partials) + gate + per-batch softmax
__global__ __launch_bounds__(1024) void k_tail(
        const float* __restrict__ wcol, const float* __restrict__ ws2,
        const unsigned char* __restrict__ bx,
        const float* __restrict__ g2, const float* __restrict__ b2,
        const float* __restrict__ Wp, const float* __restrict__ bp,
        float* __restrict__ wout) {
    const int t = threadIdx.x, lane = t & 63, wv = t >> 6;
    __shared__ float abuf[12];       // a2s[0..5], c2s[6..11]
    __shared__ float xb[4096];
    __shared__ float wred[16][2];

    if (t < HH) {
        float s = 0.f, s2 = 0.f;
        for (int b = 0; b < 4; b++) {
            int bh = b * HH + t;
#pragma unroll
            for (int sub = 0; sub < 4; sub++) {
                int blk = bh * 4 + sub;
                s += ws2[blk * 2];
                s2 += ws2[blk * 2 + 1];
            }
        }
        float m = s / 4096.f;
        float var = fmaxf(s2 / 4096.f - m * m, 0.0f);
        float r = rsqrtf(var + EPS);
        float a = r * g2[t];
        abuf[t] = a;
        abuf[6 + t] = b2[t] - m * a;
    }
    __syncthreads();

    const float bp0 = bp[0], bp1 = bp[1];
#pragma unroll
    for (int p = 0; p < 4; p++) {
        int idx = t + p * 1024;
        int b = idx >> 10, l = idx & 1023;
        float z0 = bp0, z1 = bp1;
#pragma unroll
        for (int h = 0; h < HH; h++) {
            float wn = abuf[h] * wcol[(size_t)(b * HH + h) * 1024 + l] + abuf[6 + h];
            z0 += wn * Wp[h];
            z1 += wn * Wp[HH + h];
        }
        float pc = 1.0f / (1.0f + __expf(z1 - z0));
        xb[idx] = bx[b * LL + l] ? -INFINITY : pc;
    }
    __syncthreads();

    const int bb = t >> 8, tb = t & 255;
    float4 xv = *(const float4*)&xb[bb * 1024 + tb * 4];
    float mx = fmaxf(fmaxf(xv.x, xv.y), fmaxf(xv.z, xv.w));
#pragma unroll
    for (int off = 1; off < 64; off <<= 1) mx = fmaxf(mx, __shfl_xor(mx, off));
    if (lane == 0) wred[wv][0] = mx;
    __syncthreads();
    mx = fmaxf(fmaxf(wred[bb * 4][0], wred[bb * 4 + 1][0]),
               fmaxf(wred[bb * 4 + 2][0], wred[bb * 4 + 3][0]));
    float e0 = __expf(xv.x - mx), e1 = __expf(xv.y - mx);
    float e2 = __expf(xv.z - mx), e3 = __expf(xv.w - mx);
    float ss = e0 + e1 + e2 + e3;
#pragma unroll
    for (int off = 1; off < 64; off <<= 1) ss += __shfl_xor(ss, off);
    if (lane == 0) wred[wv][1] = ss;
    __syncthreads();
    float sum = wred[bb * 4][1] + wred[bb * 4 + 1][1] + wred[bb * 4 + 2][1] + wred[bb * 4 + 3][1];
    float4 o;
    o.x = e0 / sum; o.y = e1 / sum; o.z = e2 / sum; o.w = e3 / sum;
    *(float4*)&wout[bb * 1024 + tb * 4] = o;
}

extern "C" void kernel_launch(void* const* d_in, const int* in_sizes, int n_in,
                              void* d_out, int out_size, void* d_ws, size_t ws_size,
                              hipStream_t stream) {
    const float* Q  = (const float*)d_in[0];
    const float* K  = (const float*)d_in[1];
    const float* V  = (const float*)d_in[2];
    // d_in[3] = pad_mask — derivable from bx_packed, unused
    const unsigned char* bx = (const unsigned char*)d_in[4];
    const float* g1 = (const float*)d_in[5];
    const float* b1 = (const float*)d_in[6];
    const float* g2 = (const float*)d_in[7];
    const float* b2 = (const float*)d_in[8];
    const float* Wp = (const float*)d_in[9];
    const float* bp = (const float*)d_in[10];

    float* out  = (float*)d_out;
    float* co   = out;                        // (B,H,L,L)
    float* wout = out + CO_ELEMS;             // (B,L,1)
    float* vh   = out + CO_ELEMS + W_ELEMS;   // (B,H,L,DH)

    float* ws = (float*)d_ws;                 // ~3.9 MB
    float* q2    = ws + OFF_Q2;
    float* k2    = ws + OFF_K2;
    float* wcol  = ws + OFF_WC;
    float* smP   = ws + OFF_SM;
    float* ac    = ws + OFF_AC;
    float* gdP   = ws + OFF_GDP;
    float* ws2   = ws + OFF_SS;
    float* wcolP = ws + OFF_WP;
    float* gramS = co;                        // 25 MB scratch inside co region
                                              // (fully overwritten by k_fused)

    k_rownorm<<<768, 256, 0, stream>>>(Q, K, ws);
    k_gramsum<<<dim3(24, 2, 8), 256, 0, stream>>>(Q, K, ws, gramS, smP);
    k_vh<<<3072, 256, 0, stream>>>(V, vh);
    k_gdot<<<dim3(24, 8), 256, 0, stream>>>(gramS, gdP);
    k_stats2<<<1, 256, 0, stream>>>(smP, gdP, g1, b1, ac);
    k_fused<<<dim3(32, 24), 256, 0, stream>>>(Q, K, q2, k2, ac, bx, co, wcolP);
    k_wcol_reduce<<<96, 256, 0, stream>>>(wcolP, wcol, ws2);
    k_tail<<<1, 1024, 0, stream>>>(wcol, ws2, bx, g2, b2, Wp, bp, wout);
}